// Round 7
// baseline (233.465 us; speedup 1.0000x reference)
//
#include <hip/hip_runtime.h>
#include <math.h>

// ---- problem constants ----
#define NN      4096   // nodes
#define INF_    512    // in features
#define OUTF    256    // out features
#define NHEAD   4
#define HDIM    64
#define KSPLIT  8

typedef __attribute__((ext_vector_type(8))) short  short8x;
typedef __attribute__((ext_vector_type(4))) float  float4x;

__device__ __forceinline__ unsigned short f2bf(float x) {
    union { float f; unsigned int u; } c; c.f = x;
    unsigned int r = (c.u + 0x7FFFu + ((c.u >> 16) & 1u)) >> 16;
    return (unsigned short)r;
}
__device__ __forceinline__ float bflo(unsigned int u) {
    union { unsigned int x; float f; } c; c.x = u << 16; return c.f;
}
__device__ __forceinline__ float bfhi(unsigned int u) {
    union { unsigned int x; float f; } c; c.x = u & 0xFFFF0000u; return c.f;
}

// ============================================================
// K0: b<8: wsrc/wdst[k][h] = sum_d W[h*64+d][k]*a[h][d(/+64)]
//     8<=b<2184: cast feat/W to bf16
//     b>=2184: out = bias (init for atomic accumulation)
// ============================================================
__global__ __launch_bounds__(256) void k_prep(const float* __restrict__ feat,
                                              const float* __restrict__ W,
                                              const float* __restrict__ a,
                                              const float* __restrict__ bias,
                                              unsigned short* __restrict__ featb,
                                              unsigned short* __restrict__ Wb,
                                              float* __restrict__ wsrc,
                                              float* __restrict__ wdst,
                                              float* __restrict__ out) {
    const int b = blockIdx.x;
    if (b < 8) {
        const int kk = threadIdx.x & 63, h = threadIdx.x >> 6;
        const int k = b * 64 + kk;
        float s = 0.f, d2 = 0.f;
        #pragma unroll 8
        for (int d = 0; d < 64; ++d) {
            float wv = W[(size_t)(h * HDIM + d) * INF_ + k];
            s  += wv * a[h * 2 * HDIM + d];
            d2 += wv * a[h * 2 * HDIM + HDIM + d];
        }
        wsrc[k * NHEAD + h] = s;
        wdst[k * NHEAD + h] = d2;
        return;
    }
    if (b >= 2184) {
        const int idx = (b - 2184) * 1024 + threadIdx.x * 4;
        float4x bv = *(const float4x*)&bias[idx & 255];
        *(float4x*)&out[idx] = bv;
        return;
    }
    const int bb = b - 8;
    const float* src;
    unsigned short* dst;
    int idx;
    if (bb < 2048) { src = feat; dst = featb; idx = bb * 1024 + threadIdx.x * 4; }
    else           { src = W;    dst = Wb;    idx = (bb - 2048) * 1024 + threadIdx.x * 4; }
    float4x v = *(const float4x*)(src + idx);
    ushort4 u;
    u.x = f2bf(v[0]); u.y = f2bf(v[1]); u.z = f2bf(v[2]); u.w = f2bf(v[3]);
    *(ushort4*)(dst + idx) = u;
}

// ============================================================
// K1 (merged): b<256: h=feat@W^T bf16 MFMA -> hT
//              b>=256: es/ed projections -> es + exp tables
// ============================================================
__global__ __launch_bounds__(256) void k_mid(const unsigned short* __restrict__ featb,
                                             const unsigned short* __restrict__ Wb,
                                             const float* __restrict__ feat,
                                             const float* __restrict__ wsrc,
                                             const float* __restrict__ wdst,
                                             unsigned short* __restrict__ hT,
                                             float* __restrict__ es,
                                             unsigned short* __restrict__ Bt,
                                             unsigned short* __restrict__ Dt) {
    __shared__ __align__(16) unsigned short lds_f[64 * 40];
    __shared__ __align__(16) unsigned short lds_w[64 * 40];
    const int tid = threadIdx.x;
    if (blockIdx.x >= 256) {
        // ---- edge-projection role ----
        const int r = (blockIdx.x - 256) * 16 + (tid >> 4);
        const int lane = tid & 15;
        float s[4] = {0.f, 0.f, 0.f, 0.f};
        float d[4] = {0.f, 0.f, 0.f, 0.f};
        for (int kk = 0; kk < 32; ++kk) {
            int k = kk * 16 + lane;
            float f = feat[(size_t)r * INF_ + k];
            float4x wsv = ((const float4x*)wsrc)[k];
            float4x wdv = ((const float4x*)wdst)[k];
            #pragma unroll
            for (int h = 0; h < 4; ++h) { s[h] += f * wsv[h]; d[h] += f * wdv[h]; }
        }
        #pragma unroll
        for (int off = 1; off < 16; off <<= 1) {
            #pragma unroll
            for (int h = 0; h < 4; ++h) {
                s[h] += __shfl_xor(s[h], off);
                d[h] += __shfl_xor(d[h], off);
            }
        }
        if (lane == 0) {
            #pragma unroll
            for (int h = 0; h < 4; ++h) {
                es[r * NHEAD + h] = s[h];
                Bt[r * NHEAD + h] = f2bf(__expf(d[h]));
                Dt[r * NHEAD + h] = f2bf(__expf(0.2f * d[h]));
            }
        }
        return;
    }
    // ---- h-GEMM role ----
    const int w    = tid >> 6;
    const int lane = tid & 63;
    const int lidx = lane & 15;
    const int quad = lane >> 4;
    const int o0 = (blockIdx.x & 3) * 64;
    const int i0 = (blockIdx.x >> 2) * 64;
    const int sr = tid >> 2;
    const int skq = (tid & 3) * 8;

    float4x acc[4];
    #pragma unroll
    for (int nt = 0; nt < 4; ++nt) acc[nt] = (float4x){0.f, 0.f, 0.f, 0.f};

    ushort4 pf0 = *(const ushort4*)&featb[(size_t)(i0 + sr) * INF_ + skq];
    ushort4 pf1 = *(const ushort4*)&featb[(size_t)(i0 + sr) * INF_ + skq + 4];
    ushort4 pw0 = *(const ushort4*)&Wb[(size_t)(o0 + sr) * INF_ + skq];
    ushort4 pw1 = *(const ushort4*)&Wb[(size_t)(o0 + sr) * INF_ + skq + 4];

    for (int kt = 0; kt < INF_; kt += 32) {
        __syncthreads();
        *(ushort4*)&lds_f[sr * 40 + skq]     = pf0;
        *(ushort4*)&lds_f[sr * 40 + skq + 4] = pf1;
        *(ushort4*)&lds_w[sr * 40 + skq]     = pw0;
        *(ushort4*)&lds_w[sr * 40 + skq + 4] = pw1;
        __syncthreads();
        if (kt + 32 < INF_) {
            int kn = kt + 32;
            pf0 = *(const ushort4*)&featb[(size_t)(i0 + sr) * INF_ + kn + skq];
            pf1 = *(const ushort4*)&featb[(size_t)(i0 + sr) * INF_ + kn + skq + 4];
            pw0 = *(const ushort4*)&Wb[(size_t)(o0 + sr) * INF_ + kn + skq];
            pw1 = *(const ushort4*)&Wb[(size_t)(o0 + sr) * INF_ + kn + skq + 4];
        }
        short8x af = *(const short8x*)&lds_f[(w * 16 + lidx) * 40 + quad * 8];
        short8x bw[4];
        #pragma unroll
        for (int t = 0; t < 4; ++t)
            bw[t] = *(const short8x*)&lds_w[(t * 16 + lidx) * 40 + quad * 8];
        #pragma unroll
        for (int nt = 0; nt < 4; ++nt)
            acc[nt] = __builtin_amdgcn_mfma_f32_16x16x32_bf16(af, bw[nt], acc[nt], 0, 0, 0);
    }
    #pragma unroll
    for (int nt = 0; nt < 4; ++nt) {
        int col = o0 + nt * 16 + lidx;
        int m0r = i0 + w * 16 + quad * 4;
        ushort4 u;
        u.x = f2bf(acc[nt][0]); u.y = f2bf(acc[nt][1]);
        u.z = f2bf(acc[nt][2]); u.w = f2bf(acc[nt][3]);
        *(ushort4*)&hT[(size_t)col * NN + m0r] = u;
    }
}

// ============================================================
// K2: attn rows, fully register-resident. 1 row/block, 4096 blocks.
// Each thread owns 16 j: adj (4 float4) + tables (16 uint4) loaded
// once into regs; pass1 sums -> LDS reduce -> pass2 pure VALU+store.
// pos test: B[j] >= exp(-es_i)
// ============================================================
__global__ __launch_bounds__(256, 4) void k_attn(const float* __restrict__ adj,
                                                 const float* __restrict__ es,
                                                 const unsigned short* __restrict__ Bt,
                                                 const unsigned short* __restrict__ Dt,
                                                 unsigned short* __restrict__ attn) {
    __shared__ float red[4][8];
    __shared__ float cfs[8];
    const int tid = threadIdx.x;
    const int wv  = tid >> 6;
    const int lane = tid & 63;
    const int i = blockIdx.x;

    const float4x esv = ((const float4x*)es)[i];
    float TB[4];
    #pragma unroll
    for (int h = 0; h < 4; ++h) TB[h] = __expf(-esv[h]);
    const float4x* arow4 = (const float4x*)(adj + (size_t)i * NN);
    const uint4* B4 = (const uint4*)Bt;
    const uint4* D4 = (const uint4*)Dt;

    // ---- load everything into registers (20 loads in flight) ----
    float4x av[4];
    uint4 bu[8], du[8];
    #pragma unroll
    for (int t = 0; t < 4; ++t) {
        int jv = t * 256 + tid;
        av[t] = arow4[jv];
        bu[2 * t]     = B4[jv * 2];
        bu[2 * t + 1] = B4[jv * 2 + 1];
        du[2 * t]     = D4[jv * 2];
        du[2 * t + 1] = D4[jv * 2 + 1];
    }

    // ---- pass 1: masked sums ----
    float S1[4] = {0.f, 0.f, 0.f, 0.f};
    float S2[4] = {0.f, 0.f, 0.f, 0.f};
    #pragma unroll
    for (int t = 0; t < 4; ++t) {
        const unsigned int* bup = (const unsigned int*)&bu[2 * t];
        const unsigned int* dup = (const unsigned int*)&du[2 * t];
        #pragma unroll
        for (int u = 0; u < 4; ++u) {
            bool m = av[t][u] > 0.1f;
            unsigned int bwA = bup[u * 2], bwB = bup[u * 2 + 1];
            unsigned int dwA = dup[u * 2], dwB = dup[u * 2 + 1];
            float b0 = bflo(bwA), b1 = bfhi(bwA), b2 = bflo(bwB), b3 = bfhi(bwB);
            float d0 = bflo(dwA), d1 = bfhi(dwA), d2 = bflo(dwB), d3 = bfhi(dwB);
            bool p0 = b0 >= TB[0], p1 = b1 >= TB[1], p2 = b2 >= TB[2], p3 = b3 >= TB[3];
            S1[0] += (m && p0) ? b0 : 0.f;   S2[0] += (m && !p0) ? d0 : 0.f;
            S1[1] += (m && p1) ? b1 : 0.f;   S2[1] += (m && !p1) ? d1 : 0.f;
            S1[2] += (m && p2) ? b2 : 0.f;   S2[2] += (m && !p2) ? d2 : 0.f;
            S1[3] += (m && p3) ? b3 : 0.f;   S2[3] += (m && !p3) ? d3 : 0.f;
        }
    }
    #pragma unroll
    for (int off = 1; off < 64; off <<= 1) {
        #pragma unroll
        for (int h = 0; h < 4; ++h) {
            S1[h] += __shfl_xor(S1[h], off);
            S2[h] += __shfl_xor(S2[h], off);
        }
    }
    if (lane == 0) {
        #pragma unroll
        for (int h = 0; h < 4; ++h) { red[wv][h] = S1[h]; red[wv][4 + h] = S2[h]; }
    }
    __syncthreads();
    if (tid < 8)
        cfs[tid] = red[0][tid] + red[1][tid] + red[2][tid] + red[3][tid];
    __syncthreads();
    float cA[4], cC[4];
    #pragma unroll
    for (int h = 0; h < 4; ++h) {
        float A = __expf(esv[h]), C = __expf(0.2f * esv[h]);
        float den = A * cfs[h] + C * cfs[4 + h];
        float sc = den > 0.f ? 0.25f / den : 0.f;
        cA[h] = A * sc;
        cC[h] = C * sc;
    }

    // ---- pass 2: pure VALU from registers + store ----
    unsigned short* orow = attn + (size_t)i * NN;
    #pragma unroll
    for (int t = 0; t < 4; ++t) {
        const unsigned int* bup = (const unsigned int*)&bu[2 * t];
        const unsigned int* dup = (const unsigned int*)&du[2 * t];
        ushort4 o;
        unsigned short* op = (unsigned short*)&o;
        #pragma unroll
        for (int u = 0; u < 4; ++u) {
            unsigned int bwA = bup[u * 2], bwB = bup[u * 2 + 1];
            unsigned int dwA = dup[u * 2], dwB = dup[u * 2 + 1];
            float b0 = bflo(bwA), b1 = bfhi(bwA), b2 = bflo(bwB), b3 = bfhi(bwB);
            float d0 = bflo(dwA), d1 = bfhi(dwA), d2 = bflo(dwB), d3 = bfhi(dwB);
            float p;
            p  = (b0 >= TB[0]) ? cA[0] * b0 : cC[0] * d0;
            p += (b1 >= TB[1]) ? cA[1] * b1 : cC[1] * d1;
            p += (b2 >= TB[2]) ? cA[2] * b2 : cC[2] * d2;
            p += (b3 >= TB[3]) ? cA[3] * b3 : cC[3] * d3;
            op[u] = f2bf((av[t][u] > 0.1f) ? p : 0.f);
        }
        *(ushort4*)&orow[(t * 256 + tid) * 4] = o;
    }
}

// ============================================================
// K3: out += attn[:, ks] @ h[ks, :]  (bf16 MFMA, reg prefetch,
// device-scope fp32 atomic accumulation; bias pre-loaded in out)
// ============================================================
__global__ __launch_bounds__(256) void k_out_gemm(const unsigned short* __restrict__ attn,
                                                  const unsigned short* __restrict__ hT,
                                                  float* __restrict__ out) {
    __shared__ __align__(16) unsigned short lds_a[64 * 40];
    __shared__ __align__(16) unsigned short lds_h[256 * 40];
    const int tid  = threadIdx.x;
    const int w    = tid >> 6;
    const int lane = tid & 63;
    const int lidx = lane & 15;
    const int quad = lane >> 4;
    const int i0    = blockIdx.x * 64;
    const int kbase = blockIdx.y * (NN / KSPLIT);
    const int srow = tid >> 3;      // 0..31
    const int skq  = tid & 7;

    float4x acc[4][4];
    #pragma unroll
    for (int a = 0; a < 4; ++a)
        #pragma unroll
        for (int b = 0; b < 4; ++b)
            acc[a][b] = (float4x){0.f, 0.f, 0.f, 0.f};

    ushort4 pa[2], ph[8];
    #pragma unroll
    for (int it = 0; it < 2; ++it)
        pa[it] = *(const ushort4*)&attn[(size_t)(i0 + it * 32 + srow) * NN + kbase + skq * 4];
    #pragma unroll
    for (int it = 0; it < 8; ++it)
        ph[it] = *(const ushort4*)&hT[(size_t)(it * 32 + srow) * NN + kbase + skq * 4];

    const int KSTEPS = (NN / KSPLIT) / 32;   // 16
    for (int ks = 0; ks < KSTEPS; ++ks) {
        __syncthreads();
        #pragma unroll
        for (int it = 0; it < 2; ++it)
            *(ushort4*)&lds_a[(it * 32 + srow) * 40 + skq * 4] = pa[it];
        #pragma unroll
        for (int it = 0; it < 8; ++it)
            *(ushort4*)&lds_h[(it * 32 + srow) * 40 + skq * 4] = ph[it];
        __syncthreads();
        if (ks < KSTEPS - 1) {
            const int ktn = kbase + (ks + 1) * 32;
            #pragma unroll
            for (int it = 0; it < 2; ++it)
                pa[it] = *(const ushort4*)&attn[(size_t)(i0 + it * 32 + srow) * NN + ktn + skq * 4];
            #pragma unroll
            for (int it = 0; it < 8; ++it)
                ph[it] = *(const ushort4*)&hT[(size_t)(it * 32 + srow) * NN + ktn + skq * 4];
        }
        short8x af[4], bfr[4];
        #pragma unroll
        for (int t = 0; t < 4; ++t) {
            af[t]  = *(const short8x*)&lds_a[(t * 16 + lidx) * 40 + quad * 8];
            bfr[t] = *(const short8x*)&lds_h[(w * 64 + t * 16 + lidx) * 40 + quad * 8];
        }
        #pragma unroll
        for (int it = 0; it < 4; ++it)
            #pragma unroll
            for (int nt = 0; nt < 4; ++nt)
                acc[it][nt] = __builtin_amdgcn_mfma_f32_16x16x32_bf16(
                    af[it], bfr[nt], acc[it][nt], 0, 0, 0);
    }
    #pragma unroll
    for (int it = 0; it < 4; ++it)
        #pragma unroll
        for (int nt = 0; nt < 4; ++nt) {
            int col = w * 64 + nt * 16 + lidx;
            int row0 = i0 + it * 16 + quad * 4;
            #pragma unroll
            for (int rr = 0; rr < 4; ++rr)
                __hip_atomic_fetch_add(&out[(size_t)(row0 + rr) * OUTF + col],
                                       acc[it][nt][rr],
                                       __ATOMIC_RELAXED, __HIP_MEMORY_SCOPE_AGENT);
        }
}

// ============================================================
extern "C" void kernel_launch(void* const* d_in, const int* in_sizes, int n_in,
                              void* d_out, int out_size, void* d_ws, size_t ws_size,
                              hipStream_t stream) {
    const float* feat = (const float*)d_in[0];   // [4096,512]
    const float* adj  = (const float*)d_in[1];   // [4096,4096]
    const float* W    = (const float*)d_in[2];   // [256,512]
    const float* a    = (const float*)d_in[3];   // [4,128]
    const float* bias = (const float*)d_in[4];   // [256]
    float* out = (float*)d_out;                  // [4096,256] fp32

    char* ws = (char*)d_ws;
    float*          es    = (float*)(ws + 0);                        // 64 KiB
    unsigned short* Btb   = (unsigned short*)(ws + (64u << 10));     // 32 KiB
    unsigned short* Dtb   = (unsigned short*)(ws + (96u << 10));     // 32 KiB
    float*          wsrc  = (float*)(ws + (128u << 10));             // 8 KiB
    float*          wdst  = (float*)(ws + (160u << 10));             // 8 KiB
    unsigned short* hT    = (unsigned short*)(ws + (256u << 10));    // 2 MiB
    unsigned short* attn  = (unsigned short*)(ws + (2560u << 10));   // 32 MiB
    unsigned short* featb = (unsigned short*)(ws + (2560u << 10));   // 4 MiB (dead before attn written)
    unsigned short* Wb    = (unsigned short*)(ws + (6656u << 10));   // 256 KiB (dead before attn)

    k_prep    <<<3208,             256, 0, stream>>>(feat, W, a, bias, featb, Wb, wsrc, wdst, out);
    k_mid     <<<512,              256, 0, stream>>>(featb, Wb, feat, wsrc, wdst, hT, es, Btb, Dtb);
    k_attn    <<<NN,               256, 0, stream>>>(adj, es, Btb, Dtb, attn);
    k_out_gemm<<<dim3(64, KSPLIT), 256, 0, stream>>>(attn, hT, out);
}

// Round 8
// 183.787 us; speedup vs baseline: 1.2703x; 1.2703x over previous
//
#include <hip/hip_runtime.h>
#include <math.h>

// ---- problem constants ----
#define NN      4096   // nodes
#define INF_    512    // in features
#define OUTF    256    // out features
#define NHEAD   4
#define HDIM    64
#define KSPLIT  8

typedef __attribute__((ext_vector_type(8))) short  short8x;
typedef __attribute__((ext_vector_type(4))) float  float4x;

__device__ __forceinline__ unsigned short f2bf(float x) {
    union { float f; unsigned int u; } c; c.f = x;
    unsigned int r = (c.u + 0x7FFFu + ((c.u >> 16) & 1u)) >> 16;
    return (unsigned short)r;
}
__device__ __forceinline__ float bflo(unsigned int u) {
    union { unsigned int x; float f; } c; c.x = u << 16; return c.f;
}
__device__ __forceinline__ float bfhi(unsigned int u) {
    union { unsigned int x; float f; } c; c.x = u & 0xFFFF0000u; return c.f;
}

// ============================================================
// K0: cast feat and W to bf16
// ============================================================
__global__ __launch_bounds__(256) void k_cast(const float* __restrict__ feat,
                                              const float* __restrict__ W,
                                              unsigned short* __restrict__ featb,
                                              unsigned short* __restrict__ Wb) {
    const int b = blockIdx.x;
    const float* src;
    unsigned short* dst;
    int idx;
    if (b < 2048) { src = feat; dst = featb; idx = b * 1024 + threadIdx.x * 4; }
    else          { src = W;    dst = Wb;    idx = (b - 2048) * 1024 + threadIdx.x * 4; }
    float4x v = *(const float4x*)(src + idx);
    ushort4 u;
    u.x = f2bf(v[0]); u.y = f2bf(v[1]); u.z = f2bf(v[2]); u.w = f2bf(v[3]);
    *(ushort4*)(dst + idx) = u;
}

// ============================================================
// K1: h = feat @ W^T (bf16 MFMA, 64 blocks, full OUTF per block)
// epilogue: hT bf16 write + es/ed per-head dots from registers
// -> es + exp tables Bt=exp(ed), Dt=exp(0.2 ed)
// ============================================================
__global__ __launch_bounds__(256) void k_hedge(const unsigned short* __restrict__ featb,
                                               const unsigned short* __restrict__ Wb,
                                               const float* __restrict__ a,
                                               unsigned short* __restrict__ hT,
                                               float* __restrict__ es,
                                               unsigned short* __restrict__ Bt,
                                               unsigned short* __restrict__ Dt) {
    __shared__ __align__(16) unsigned short lds_f[64 * 40];
    __shared__ __align__(16) unsigned short lds_w[256 * 40];
    const int tid  = threadIdx.x;
    const int w    = tid >> 6;
    const int lane = tid & 63;
    const int lidx = lane & 15;
    const int quad = lane >> 4;
    const int i0   = blockIdx.x * 64;
    const int sr = tid >> 2;
    const int skq = (tid & 3) * 8;

    float4x acc[4][4];
    #pragma unroll
    for (int p = 0; p < 4; ++p)
        #pragma unroll
        for (int q = 0; q < 4; ++q)
            acc[p][q] = (float4x){0.f, 0.f, 0.f, 0.f};

    for (int kt = 0; kt < INF_; kt += 32) {
        __syncthreads();
        *(ushort4*)&lds_f[sr * 40 + skq]     = *(const ushort4*)&featb[(size_t)(i0 + sr) * INF_ + kt + skq];
        *(ushort4*)&lds_f[sr * 40 + skq + 4] = *(const ushort4*)&featb[(size_t)(i0 + sr) * INF_ + kt + skq + 4];
        #pragma unroll
        for (int itr = 0; itr < 4; ++itr) {
            int n = itr * 64 + sr;
            *(ushort4*)&lds_w[n * 40 + skq]     = *(const ushort4*)&Wb[(size_t)n * INF_ + kt + skq];
            *(ushort4*)&lds_w[n * 40 + skq + 4] = *(const ushort4*)&Wb[(size_t)n * INF_ + kt + skq + 4];
        }
        __syncthreads();
        short8x af[4], bw[4];
        #pragma unroll
        for (int t = 0; t < 4; ++t) {
            af[t] = *(const short8x*)&lds_f[(t * 16 + lidx) * 40 + quad * 8];
            bw[t] = *(const short8x*)&lds_w[(w * 64 + t * 16 + lidx) * 40 + quad * 8];
        }
        #pragma unroll
        for (int it = 0; it < 4; ++it)
            #pragma unroll
            for (int nt = 0; nt < 4; ++nt)
                acc[it][nt] = __builtin_amdgcn_mfma_f32_16x16x32_bf16(
                    af[it], bw[nt], acc[it][nt], 0, 0, 0);
    }
    // ---- hT write (D layout: col=lane&15 block w*64+nt*16, row=quad*4+r) ----
    #pragma unroll
    for (int it = 0; it < 4; ++it)
        #pragma unroll
        for (int nt = 0; nt < 4; ++nt) {
            int col = w * 64 + nt * 16 + lidx;
            int m0r = i0 + it * 16 + quad * 4;
            ushort4 u;
            u.x = f2bf(acc[it][nt][0]); u.y = f2bf(acc[it][nt][1]);
            u.z = f2bf(acc[it][nt][2]); u.w = f2bf(acc[it][nt][3]);
            *(ushort4*)&hT[(size_t)col * NN + m0r] = u;
        }
    // ---- es/ed epilogue: head = w; col_d = nt*16 + lidx ----
    float asrc[4], adst[4];
    #pragma unroll
    for (int nt = 0; nt < 4; ++nt) {
        asrc[nt] = a[w * 2 * HDIM + nt * 16 + lidx];
        adst[nt] = a[w * 2 * HDIM + HDIM + nt * 16 + lidx];
    }
    #pragma unroll
    for (int it = 0; it < 4; ++it)
        #pragma unroll
        for (int r = 0; r < 4; ++r) {
            float s = 0.f, d = 0.f;
            #pragma unroll
            for (int nt = 0; nt < 4; ++nt) {
                s += acc[it][nt][r] * asrc[nt];
                d += acc[it][nt][r] * adst[nt];
            }
            #pragma unroll
            for (int off = 1; off < 16; off <<= 1) {
                s += __shfl_xor(s, off);
                d += __shfl_xor(d, off);
            }
            if (lidx == 0) {
                int row = i0 + it * 16 + quad * 4 + r;
                es[row * NHEAD + w] = s;
                Bt[row * NHEAD + w] = f2bf(__expf(d));
                Dt[row * NHEAD + w] = f2bf(__expf(0.2f * d));
            }
        }
}

// ============================================================
// K2: fused den + attn-row write. 1 row/block, 4096 blocks (16/CU).
// adj cached in regs (16 VGPR) across passes; tables re-read inline
// from L2. All predicated; pos test: B[j] >= exp(-es_i).
// ============================================================
__global__ __launch_bounds__(256) void k_attn(const float* __restrict__ adj,
                                              const float* __restrict__ es,
                                              const unsigned short* __restrict__ Bt,
                                              const unsigned short* __restrict__ Dt,
                                              unsigned short* __restrict__ attn) {
    __shared__ float red[4][8];
    __shared__ float cfs[8];
    const int tid = threadIdx.x;
    const int wv  = tid >> 6;
    const int lane = tid & 63;
    const int i = blockIdx.x;

    const float4x esv = ((const float4x*)es)[i];
    float TB[4];
    #pragma unroll
    for (int h = 0; h < 4; ++h) TB[h] = __expf(-esv[h]);
    const float4x* arow4 = (const float4x*)(adj + (size_t)i * NN);
    const uint4* B4 = (const uint4*)Bt;
    const uint4* D4 = (const uint4*)Dt;

    // ---- pass 1: masked sums (adj row -> regs, tables inline) ----
    float4x av[4];
    float S1[4] = {0.f, 0.f, 0.f, 0.f};
    float S2[4] = {0.f, 0.f, 0.f, 0.f};
    #pragma unroll
    for (int t = 0; t < 4; ++t) {
        int jv = t * 256 + tid;
        av[t] = arow4[jv];
        uint4 bu0 = B4[jv * 2], bu1 = B4[jv * 2 + 1];
        uint4 du0 = D4[jv * 2], du1 = D4[jv * 2 + 1];
        unsigned int bwv[8] = {bu0.x, bu0.y, bu0.z, bu0.w, bu1.x, bu1.y, bu1.z, bu1.w};
        unsigned int dwv[8] = {du0.x, du0.y, du0.z, du0.w, du1.x, du1.y, du1.z, du1.w};
        #pragma unroll
        for (int u = 0; u < 4; ++u) {
            bool m = av[t][u] > 0.1f;
            float b0 = bflo(bwv[u * 2]), b1 = bfhi(bwv[u * 2]);
            float b2 = bflo(bwv[u * 2 + 1]), b3 = bfhi(bwv[u * 2 + 1]);
            float d0 = bflo(dwv[u * 2]), d1 = bfhi(dwv[u * 2]);
            float d2 = bflo(dwv[u * 2 + 1]), d3 = bfhi(dwv[u * 2 + 1]);
            bool p0 = b0 >= TB[0], p1 = b1 >= TB[1], p2 = b2 >= TB[2], p3 = b3 >= TB[3];
            S1[0] += (m && p0) ? b0 : 0.f;   S2[0] += (m && !p0) ? d0 : 0.f;
            S1[1] += (m && p1) ? b1 : 0.f;   S2[1] += (m && !p1) ? d1 : 0.f;
            S1[2] += (m && p2) ? b2 : 0.f;   S2[2] += (m && !p2) ? d2 : 0.f;
            S1[3] += (m && p3) ? b3 : 0.f;   S2[3] += (m && !p3) ? d3 : 0.f;
        }
    }
    #pragma unroll
    for (int off = 1; off < 64; off <<= 1) {
        #pragma unroll
        for (int h = 0; h < 4; ++h) {
            S1[h] += __shfl_xor(S1[h], off);
            S2[h] += __shfl_xor(S2[h], off);
        }
    }
    if (lane == 0) {
        #pragma unroll
        for (int h = 0; h < 4; ++h) { red[wv][h] = S1[h]; red[wv][4 + h] = S2[h]; }
    }
    __syncthreads();
    if (tid < 8)
        cfs[tid] = red[0][tid] + red[1][tid] + red[2][tid] + red[3][tid];
    __syncthreads();
    float cA[4], cC[4];
    #pragma unroll
    for (int h = 0; h < 4; ++h) {
        float A = __expf(esv[h]), C = __expf(0.2f * esv[h]);
        float den = A * cfs[h] + C * cfs[4 + h];
        float sc = den > 0.f ? 0.25f / den : 0.f;
        cA[h] = A * sc;
        cC[h] = C * sc;
    }

    // ---- pass 2: re-read tables (L2-hot), adj from regs, store ----
    unsigned short* orow = attn + (size_t)i * NN;
    #pragma unroll
    for (int t = 0; t < 4; ++t) {
        int jv = t * 256 + tid;
        uint4 bu0 = B4[jv * 2], bu1 = B4[jv * 2 + 1];
        uint4 du0 = D4[jv * 2], du1 = D4[jv * 2 + 1];
        unsigned int bwv[8] = {bu0.x, bu0.y, bu0.z, bu0.w, bu1.x, bu1.y, bu1.z, bu1.w};
        unsigned int dwv[8] = {du0.x, du0.y, du0.z, du0.w, du1.x, du1.y, du1.z, du1.w};
        ushort4 o;
        unsigned short* op = (unsigned short*)&o;
        #pragma unroll
        for (int u = 0; u < 4; ++u) {
            float b0 = bflo(bwv[u * 2]), b1 = bfhi(bwv[u * 2]);
            float b2 = bflo(bwv[u * 2 + 1]), b3 = bfhi(bwv[u * 2 + 1]);
            float d0 = bflo(dwv[u * 2]), d1 = bfhi(dwv[u * 2]);
            float d2 = bflo(dwv[u * 2 + 1]), d3 = bfhi(dwv[u * 2 + 1]);
            float p;
            p  = (b0 >= TB[0]) ? cA[0] * b0 : cC[0] * d0;
            p += (b1 >= TB[1]) ? cA[1] * b1 : cC[1] * d1;
            p += (b2 >= TB[2]) ? cA[2] * b2 : cC[2] * d2;
            p += (b3 >= TB[3]) ? cA[3] * b3 : cC[3] * d3;
            op[u] = f2bf((av[t][u] > 0.1f) ? p : 0.f);
        }
        *(ushort4*)&orow[jv * 4] = o;
    }
}

// ============================================================
// K3: partials[s] = attn[:, ks] @ h[ks, :]  (bf16 MFMA, reg prefetch)
// ============================================================
__global__ __launch_bounds__(256) void k_out_gemm(const unsigned short* __restrict__ attn,
                                                  const unsigned short* __restrict__ hT,
                                                  float* __restrict__ partials) {
    __shared__ __align__(16) unsigned short lds_a[64 * 40];
    __shared__ __align__(16) unsigned short lds_h[256 * 40];
    const int tid  = threadIdx.x;
    const int w    = tid >> 6;
    const int lane = tid & 63;
    const int lidx = lane & 15;
    const int quad = lane >> 4;
    const int i0    = blockIdx.x * 64;
    const int kbase = blockIdx.y * (NN / KSPLIT);
    const int srow = tid >> 3;      // 0..31
    const int skq  = tid & 7;

    float4x acc[4][4];
    #pragma unroll
    for (int p = 0; p < 4; ++p)
        #pragma unroll
        for (int q = 0; q < 4; ++q)
            acc[p][q] = (float4x){0.f, 0.f, 0.f, 0.f};

    ushort4 pa[2], ph[8];
    #pragma unroll
    for (int it = 0; it < 2; ++it)
        pa[it] = *(const ushort4*)&attn[(size_t)(i0 + it * 32 + srow) * NN + kbase + skq * 4];
    #pragma unroll
    for (int it = 0; it < 8; ++it)
        ph[it] = *(const ushort4*)&hT[(size_t)(it * 32 + srow) * NN + kbase + skq * 4];

    const int KSTEPS = (NN / KSPLIT) / 32;   // 16
    for (int ks = 0; ks < KSTEPS; ++ks) {
        __syncthreads();
        #pragma unroll
        for (int it = 0; it < 2; ++it)
            *(ushort4*)&lds_a[(it * 32 + srow) * 40 + skq * 4] = pa[it];
        #pragma unroll
        for (int it = 0; it < 8; ++it)
            *(ushort4*)&lds_h[(it * 32 + srow) * 40 + skq * 4] = ph[it];
        __syncthreads();
        if (ks < KSTEPS - 1) {
            const int ktn = kbase + (ks + 1) * 32;
            #pragma unroll
            for (int it = 0; it < 2; ++it)
                pa[it] = *(const ushort4*)&attn[(size_t)(i0 + it * 32 + srow) * NN + ktn + skq * 4];
            #pragma unroll
            for (int it = 0; it < 8; ++it)
                ph[it] = *(const ushort4*)&hT[(size_t)(it * 32 + srow) * NN + ktn + skq * 4];
        }
        short8x af[4], bfr[4];
        #pragma unroll
        for (int t = 0; t < 4; ++t) {
            af[t]  = *(const short8x*)&lds_a[(t * 16 + lidx) * 40 + quad * 8];
            bfr[t] = *(const short8x*)&lds_h[(w * 64 + t * 16 + lidx) * 40 + quad * 8];
        }
        #pragma unroll
        for (int it = 0; it < 4; ++it)
            #pragma unroll
            for (int nt = 0; nt < 4; ++nt)
                acc[it][nt] = __builtin_amdgcn_mfma_f32_16x16x32_bf16(
                    af[it], bfr[nt], acc[it][nt], 0, 0, 0);
    }
    float* pbase = partials + (size_t)blockIdx.y * NN * OUTF;
    #pragma unroll
    for (int it = 0; it < 4; ++it)
        #pragma unroll
        for (int nt = 0; nt < 4; ++nt)
            #pragma unroll
            for (int rr = 0; rr < 4; ++rr) {
                int row = i0 + it * 16 + quad * 4 + rr;
                int col = w * 64 + nt * 16 + lidx;
                pbase[(size_t)row * OUTF + col] = acc[it][nt][rr];
            }
}

// ============================================================
// K4: out = sum_s partials[s] + bias
// ============================================================
__global__ __launch_bounds__(256) void k_reduce_out(const float* __restrict__ partials,
                                                    const float* __restrict__ bias,
                                                    float* __restrict__ out) {
    const int i = blockIdx.x;
    const int n = threadIdx.x;
    float acc = bias[n];
    #pragma unroll
    for (int s = 0; s < KSPLIT; ++s)
        acc += partials[((size_t)s * NN + i) * OUTF + n];
    out[(size_t)i * OUTF + n] = acc;
}

// ============================================================
extern "C" void kernel_launch(void* const* d_in, const int* in_sizes, int n_in,
                              void* d_out, int out_size, void* d_ws, size_t ws_size,
                              hipStream_t stream) {
    const float* feat = (const float*)d_in[0];   // [4096,512]
    const float* adj  = (const float*)d_in[1];   // [4096,4096]
    const float* W    = (const float*)d_in[2];   // [256,512]
    const float* a    = (const float*)d_in[3];   // [4,128]
    const float* bias = (const float*)d_in[4];   // [256]
    float* out = (float*)d_out;                  // [4096,256] fp32

    char* ws = (char*)d_ws;
    float*          es    = (float*)(ws + 0);                        // 64 KiB
    unsigned short* Btb   = (unsigned short*)(ws + (64u << 10));     // 32 KiB
    unsigned short* Dtb   = (unsigned short*)(ws + (96u << 10));     // 32 KiB
    unsigned short* hT    = (unsigned short*)(ws + (256u << 10));    // 2 MiB
    unsigned short* attn  = (unsigned short*)(ws + (2560u << 10));   // 32 MiB
    unsigned short* featb = (unsigned short*)(ws + (2560u << 10));   // 4 MiB (dead before attn written)
    unsigned short* Wb    = (unsigned short*)(ws + (6656u << 10));   // 256 KiB (dead before attn)
    float*          partials = (float*)(ws + (35328u << 10));        // 32 MiB

    k_cast      <<<2176,             256, 0, stream>>>(feat, W, featb, Wb);
    k_hedge     <<<64,               256, 0, stream>>>(featb, Wb, a, hT, es, Btb, Dtb);
    k_attn      <<<NN,               256, 0, stream>>>(adj, es, Btb, Dtb, attn);
    k_out_gemm  <<<dim3(64, KSPLIT), 256, 0, stream>>>(attn, hT, partials);
    k_reduce_out<<<NN,               256, 0, stream>>>(partials, bias, out);
}